// Round 1
// baseline (168.215 us; speedup 1.0000x reference)
//
#include <hip/hip_runtime.h>
#include <hip/hip_bf16.h>
#include <stdint.h>

#define NN 8192
#define HH 256
#define GG 256

typedef __bf16 bf16x8 __attribute__((ext_vector_type(8)));
typedef float f32x4 __attribute__((ext_vector_type(4)));

__device__ __forceinline__ ushort f2bf(float f) {
  union { float f; uint32_t u; } v; v.f = f;
  uint32_t u = v.u;
  u += 0x7fffu + ((u >> 16) & 1u);   // RNE
  return (ushort)(u >> 16);
}
__device__ __forceinline__ float bf2f(ushort h) {
  union { uint32_t u; float f; } v; v.u = ((uint32_t)h) << 16;
  return v.f;
}

// ---------------- conversion kernels ----------------
__global__ __launch_bounds__(256) void k_convert_x(const float* __restrict__ x,
                                                   ushort* __restrict__ xb) {
  int i = (blockIdx.x * 256 + threadIdx.x) * 4;
  float4 v = *(const float4*)(x + i);
  ushort4 o;
  o.x = f2bf(v.x); o.y = f2bf(v.y); o.z = f2bf(v.z); o.w = f2bf(v.w);
  *(ushort4*)(xb + i) = o;
}

// transpose+convert 3 weight matrices [256][256] f32 -> WT bf16 [n][k]
__global__ __launch_bounds__(256) void k_conv_wT(const float* __restrict__ w0,
                                                 const float* __restrict__ w1,
                                                 const float* __restrict__ w2,
                                                 ushort* __restrict__ o0,
                                                 ushort* __restrict__ o1,
                                                 ushort* __restrict__ o2) {
  const float* w = (blockIdx.y == 0) ? w0 : (blockIdx.y == 1) ? w1 : w2;
  ushort* o = (blockIdx.y == 0) ? o0 : (blockIdx.y == 1) ? o1 : o2;
  int nrow = blockIdx.x;
  int k = threadIdx.x;
  o[nrow * HH + k] = f2bf(w[k * HH + nrow]);
}

// graph boundaries: rs[g] = lower_bound(batch, g), rs[GG] = NN
__global__ __launch_bounds__(256) void k_rowstart(const int* __restrict__ batch,
                                                  int* __restrict__ rs) {
  int g = blockIdx.x * 256 + threadIdx.x;
  if (g > GG) return;
  if (g == GG) { rs[GG] = NN; return; }
  int lo = 0, hi = NN;
  while (lo < hi) { int mid = (lo + hi) >> 1; if (batch[mid] < g) lo = mid + 1; else hi = mid; }
  rs[g] = lo;
}

// ---------------- MFMA bf16 GEMM: C[M,256] = A[M,256] @ B + bias (opt relu) ---------
// BT is B transposed: BT[n][k], bf16. Block = 4 waves; wave computes 16 rows x 64 cols.
// grid (M/64, 256/64)
__global__ __launch_bounds__(256) void k_gemm(const ushort* __restrict__ A,
                                              const ushort* __restrict__ BT,
                                              const float* __restrict__ bias,
                                              ushort* __restrict__ obf,
                                              float* __restrict__ of,
                                              int relu) {
  const int lane = threadIdx.x & 63;
  const int wid = threadIdx.x >> 6;
  const int rowbase = blockIdx.x * 64 + wid * 16;
  const int nbase = blockIdx.y * 64;
  const int l15 = lane & 15;
  const int koff = (lane >> 4) * 8;
  f32x4 acc0 = {0.f, 0.f, 0.f, 0.f};
  f32x4 acc1 = acc0, acc2 = acc0, acc3 = acc0;
  const ushort* arow = A + (size_t)(rowbase + l15) * HH + koff;
  const ushort* b0 = BT + (size_t)(nbase + l15) * HH + koff;
#pragma unroll
  for (int kk = 0; kk < HH; kk += 32) {
    bf16x8 a = *(const bf16x8*)(arow + kk);
    bf16x8 w0 = *(const bf16x8*)(b0 + kk);
    bf16x8 w1 = *(const bf16x8*)(b0 + 16 * HH + kk);
    bf16x8 w2 = *(const bf16x8*)(b0 + 32 * HH + kk);
    bf16x8 w3 = *(const bf16x8*)(b0 + 48 * HH + kk);
    acc0 = __builtin_amdgcn_mfma_f32_16x16x32_bf16(a, w0, acc0, 0, 0, 0);
    acc1 = __builtin_amdgcn_mfma_f32_16x16x32_bf16(a, w1, acc1, 0, 0, 0);
    acc2 = __builtin_amdgcn_mfma_f32_16x16x32_bf16(a, w2, acc2, 0, 0, 0);
    acc3 = __builtin_amdgcn_mfma_f32_16x16x32_bf16(a, w3, acc3, 0, 0, 0);
  }
  const int rout = rowbase + (lane >> 4) * 4;
#pragma unroll
  for (int nt = 0; nt < 4; nt++) {
    f32x4 acc = nt == 0 ? acc0 : nt == 1 ? acc1 : nt == 2 ? acc2 : acc3;
    int ncol = nbase + nt * 16 + l15;
    float bv = bias[ncol];
#pragma unroll
    for (int i = 0; i < 4; i++) {
      float vv = acc[i] + bv;
      if (relu) vv = fmaxf(vv, 0.f);
      size_t oidx = (size_t)(rout + i) * HH + ncol;
      if (obf) obf[oidx] = f2bf(vv);
      else     of[oidx] = vv;
    }
  }
}

// ---------------- per-graph attention + aggregation ----------------
__device__ __forceinline__ float dot256(const float* __restrict__ a,
                                        const float* __restrict__ b) {
  float acc = 0.f;
#pragma unroll 4
  for (int k = 0; k < HH; k += 4) {
    float4 x = *(const float4*)(a + k);
    float4 y = *(const float4*)(b + k);
    acc = fmaf(x.x, y.x, acc);
    acc = fmaf(x.y, y.y, acc);
    acc = fmaf(x.z, y.z, acc);
    acc = fmaf(x.w, y.w, acc);
  }
  return acc;
}

// one block (4 waves) per graph; assumes n <= 256 (realized max ~60 for this input)
__global__ __launch_bounds__(256) void k_attn(const float* __restrict__ s,
                                              const ushort* __restrict__ h,
                                              const int* __restrict__ rs,
                                              float* __restrict__ xagg) {
  int g = blockIdx.x;
  int r0 = rs[g], r1 = rs[g + 1];
  int n = r1 - r0;
  if (n > 256) n = 256;  // safety clamp (never hit for this input)
  __shared__ float colw[256];
  colw[threadIdx.x] = 0.f;
  __syncthreads();
  int wid = threadIdx.x >> 6, lane = threadIdx.x & 63;
  for (int i = wid; i < n; i += 4) {
    const float* si = s + (size_t)(r0 + i) * HH;
    float d0 = -1e30f, d1 = -1e30f, d2 = -1e30f, d3 = -1e30f;
    int j0 = lane, j1 = lane + 64, j2 = lane + 128, j3 = lane + 192;
    if (j0 < n) d0 = dot256(si, s + (size_t)(r0 + j0) * HH);
    if (j1 < n) d1 = dot256(si, s + (size_t)(r0 + j1) * HH);
    if (j2 < n) d2 = dot256(si, s + (size_t)(r0 + j2) * HH);
    if (j3 < n) d3 = dot256(si, s + (size_t)(r0 + j3) * HH);
    float m = fmaxf(fmaxf(d0, d1), fmaxf(d2, d3));
#pragma unroll
    for (int off = 32; off; off >>= 1) m = fmaxf(m, __shfl_xor(m, off));
    float e0 = (j0 < n) ? __expf(d0 - m) : 0.f;
    float e1 = (j1 < n) ? __expf(d1 - m) : 0.f;
    float e2 = (j2 < n) ? __expf(d2 - m) : 0.f;
    float e3 = (j3 < n) ? __expf(d3 - m) : 0.f;
    float ss = e0 + e1 + e2 + e3;
#pragma unroll
    for (int off = 32; off; off >>= 1) ss += __shfl_xor(ss, off);
    float inv = 1.f / ss;
    if (j0 < n) atomicAdd(&colw[j0], e0 * inv);
    if (j1 < n) atomicAdd(&colw[j1], e1 * inv);
    if (j2 < n) atomicAdd(&colw[j2], e2 * inv);
    if (j3 < n) atomicAdd(&colw[j3], e3 * inv);
  }
  __syncthreads();
  // xagg[g][c] = sum_j colw[j] * h[r0+j][c]
  int c = threadIdx.x;
  float agg = 0.f;
  for (int jj = 0; jj < n; jj++)
    agg = fmaf(colw[jj], bf2f(h[(size_t)(r0 + jj) * HH + c]), agg);
  xagg[(size_t)g * HH + c] = agg;
}

// ---------------- rho: out = relu(relu(xagg@r1w+r1b)@r2w+r2b), [256,256] ----------
__global__ __launch_bounds__(256) void k_rho(const float* __restrict__ xagg,
                                             const float* __restrict__ r1w,
                                             const float* __restrict__ r1b,
                                             const float* __restrict__ r2w,
                                             const float* __restrict__ r2b,
                                             float* __restrict__ out) {
  int g = blockIdx.x;
  int t = threadIdx.x;
  __shared__ float xa[256], t1[256];
  xa[t] = xagg[(size_t)g * HH + t];
  __syncthreads();
  float acc = r1b[t];
#pragma unroll 8
  for (int k = 0; k < HH; k++) acc = fmaf(xa[k], r1w[k * HH + t], acc);
  t1[t] = fmaxf(acc, 0.f);
  __syncthreads();
  acc = r2b[t];
#pragma unroll 8
  for (int k = 0; k < HH; k++) acc = fmaf(t1[k], r2w[k * HH + t], acc);
  out[(size_t)g * HH + t] = fmaxf(acc, 0.f);
}

// ---------------- launcher ----------------
extern "C" void kernel_launch(void* const* d_in, const int* in_sizes, int n_in,
                              void* d_out, int out_size, void* d_ws, size_t ws_size,
                              hipStream_t stream) {
  const float* x   = (const float*)d_in[0];
  const int* batch = (const int*)d_in[1];
  const float* aw  = (const float*)d_in[3];
  const float* ab  = (const float*)d_in[4];
  const float* p1w = (const float*)d_in[5];
  const float* p1b = (const float*)d_in[6];
  const float* p2w = (const float*)d_in[7];
  const float* p2b = (const float*)d_in[8];
  const float* r1w = (const float*)d_in[9];
  const float* r1b = (const float*)d_in[10];
  const float* r2w = (const float*)d_in[11];
  const float* r2b = (const float*)d_in[12];
  float* out = (float*)d_out;

  char* ws = (char*)d_ws;
  ushort* xb   = (ushort*)(ws);                                   // 4 MB
  ushort* h1b  = (ushort*)(ws + (size_t)4 * 1024 * 1024);         // 4 MB
  ushort* hb   = (ushort*)(ws + (size_t)8 * 1024 * 1024);         // 4 MB
  float*  sbuf = (float*)(ws + (size_t)12 * 1024 * 1024);         // 8 MB
  ushort* wT1  = (ushort*)(ws + (size_t)20 * 1024 * 1024);        // 128 KB
  ushort* wT2  = wT1 + 65536;                                     // 128 KB
  ushort* wTa  = wT2 + 65536;                                     // 128 KB
  float*  xagg = (float*)(ws + (size_t)20 * 1024 * 1024 + 512 * 1024);  // 256 KB
  int*    rsb  = (int*)(ws + (size_t)20 * 1024 * 1024 + 512 * 1024 + 256 * 1024);

  k_convert_x<<<dim3(2048), dim3(256), 0, stream>>>(x, xb);
  k_conv_wT<<<dim3(256, 3), dim3(256), 0, stream>>>(p1w, p2w, aw, wT1, wT2, wTa);
  k_rowstart<<<dim3(2), dim3(256), 0, stream>>>(batch, rsb);
  k_gemm<<<dim3(128, 4), dim3(256), 0, stream>>>(xb, wT1, p1b, h1b, (float*)nullptr, 1);
  k_gemm<<<dim3(128, 4), dim3(256), 0, stream>>>(h1b, wT2, p2b, hb, (float*)nullptr, 1);
  k_gemm<<<dim3(128, 4), dim3(256), 0, stream>>>(hb, wTa, ab, (ushort*)nullptr, sbuf, 0);
  k_attn<<<dim3(256), dim3(256), 0, stream>>>(sbuf, hb, rsb, xagg);
  k_rho<<<dim3(256), dim3(256), 0, stream>>>(xagg, r1w, r1b, r2w, r2b, out);
}

// Round 2
// 76.983 us; speedup vs baseline: 2.1851x; 2.1851x over previous
//
#include <hip/hip_runtime.h>
#include <hip/hip_bf16.h>
#include <stdint.h>

#define NN 8192
#define HH 256
#define GG 256

typedef __bf16 bf16x8 __attribute__((ext_vector_type(8)));
typedef float f32x4 __attribute__((ext_vector_type(4)));

__device__ __forceinline__ ushort f2bf(float f) {
  union { float f; uint32_t u; } v; v.f = f;
  uint32_t u = v.u;
  u += 0x7fffu + ((u >> 16) & 1u);   // RNE
  return (ushort)(u >> 16);
}
__device__ __forceinline__ float bf2f(ushort h) {
  union { uint32_t u; float f; } v; v.u = ((uint32_t)h) << 16;
  return v.f;
}

// ---------------- fused prep: convert x, transpose+convert weights, rowstarts ----
__global__ __launch_bounds__(256) void k_prep(const float* __restrict__ x,
                                              ushort* __restrict__ xb,
                                              const float* __restrict__ w0,
                                              const float* __restrict__ w1,
                                              const float* __restrict__ w2,
                                              ushort* __restrict__ o0,
                                              ushort* __restrict__ o1,
                                              ushort* __restrict__ o2,
                                              const int* __restrict__ batch,
                                              int* __restrict__ rs) {
  int b = blockIdx.x, t = threadIdx.x;
  if (b < 2048) {
    int i = (b * 256 + t) * 4;
    float4 v = *(const float4*)(x + i);
    ushort4 o;
    o.x = f2bf(v.x); o.y = f2bf(v.y); o.z = f2bf(v.z); o.w = f2bf(v.w);
    *(ushort4*)(xb + i) = o;
  } else if (b < 2816) {
    int bb = b - 2048;
    int mat = bb >> 8, nrow = bb & 255;
    const float* w = mat == 0 ? w0 : mat == 1 ? w1 : w2;
    ushort* o = mat == 0 ? o0 : mat == 1 ? o1 : o2;
    o[nrow * HH + t] = f2bf(w[t * HH + nrow]);
  } else {
    for (int g = t; g <= GG; g += 256) {
      if (g == GG) { rs[GG] = NN; continue; }
      int lo = 0, hi = NN;
      while (lo < hi) { int mid = (lo + hi) >> 1; if (batch[mid] < g) lo = mid + 1; else hi = mid; }
      rs[g] = lo;
    }
  }
}

// ---------------- MFMA bf16 GEMM: C[M,256] = A[M,256] @ B + bias (opt relu) ---------
// BT is B transposed: BT[n][k], bf16. Block = 4 waves; wave computes 16 rows x 64 cols.
// grid (M/64, 256/64)
__global__ __launch_bounds__(256) void k_gemm(const ushort* __restrict__ A,
                                              const ushort* __restrict__ BT,
                                              const float* __restrict__ bias,
                                              ushort* __restrict__ obf,
                                              int relu) {
  const int lane = threadIdx.x & 63;
  const int wid = threadIdx.x >> 6;
  const int rowbase = blockIdx.x * 64 + wid * 16;
  const int nbase = blockIdx.y * 64;
  const int l15 = lane & 15;
  const int koff = (lane >> 4) * 8;
  f32x4 acc0 = {0.f, 0.f, 0.f, 0.f};
  f32x4 acc1 = acc0, acc2 = acc0, acc3 = acc0;
  const ushort* arow = A + (size_t)(rowbase + l15) * HH + koff;
  const ushort* b0 = BT + (size_t)(nbase + l15) * HH + koff;
#pragma unroll
  for (int kk = 0; kk < HH; kk += 32) {
    bf16x8 a = *(const bf16x8*)(arow + kk);
    bf16x8 w0 = *(const bf16x8*)(b0 + kk);
    bf16x8 w1 = *(const bf16x8*)(b0 + 16 * HH + kk);
    bf16x8 w2 = *(const bf16x8*)(b0 + 32 * HH + kk);
    bf16x8 w3 = *(const bf16x8*)(b0 + 48 * HH + kk);
    acc0 = __builtin_amdgcn_mfma_f32_16x16x32_bf16(a, w0, acc0, 0, 0, 0);
    acc1 = __builtin_amdgcn_mfma_f32_16x16x32_bf16(a, w1, acc1, 0, 0, 0);
    acc2 = __builtin_amdgcn_mfma_f32_16x16x32_bf16(a, w2, acc2, 0, 0, 0);
    acc3 = __builtin_amdgcn_mfma_f32_16x16x32_bf16(a, w3, acc3, 0, 0, 0);
  }
  const int rout = rowbase + (lane >> 4) * 4;
#pragma unroll
  for (int nt = 0; nt < 4; nt++) {
    f32x4 acc = nt == 0 ? acc0 : nt == 1 ? acc1 : nt == 2 ? acc2 : acc3;
    int ncol = nbase + nt * 16 + l15;
    float bv = bias[ncol];
#pragma unroll
    for (int i = 0; i < 4; i++) {
      float vv = acc[i] + bv;
      if (relu) vv = fmaxf(vv, 0.f);
      obf[(size_t)(rout + i) * HH + ncol] = f2bf(vv);
    }
  }
}

// ---------------- per-graph attention + aggregation (MFMA fast path, n<=64) -------
__device__ __forceinline__ float dotbf(const ushort* __restrict__ a,
                                       const ushort* __restrict__ b) {
  float acc = 0.f;
  for (int k = 0; k < HH; k += 2) {
    acc = fmaf(bf2f(a[k]), bf2f(b[k]), acc);
    acc = fmaf(bf2f(a[k + 1]), bf2f(b[k + 1]), acc);
  }
  return acc;
}

__global__ __launch_bounds__(256) void k_attn(const ushort* __restrict__ sb,
                                              const ushort* __restrict__ h,
                                              const int* __restrict__ rs,
                                              float* __restrict__ xagg) {
  int g = blockIdx.x;
  int r0 = rs[g], r1 = rs[g + 1];
  int n = r1 - r0;
  __shared__ ushort st[64 * 256];   // swizzled 16B chunks
  __shared__ float colw[256];
  int tid = threadIdx.x;
  colw[tid] = 0.f;
  if (n <= 64) {
    // stage s rows (zero-padded to 64) into LDS, swizzle chunk c ^= (row&7)
    for (int ch = tid; ch < 64 * 32; ch += 256) {
      int row = ch >> 5, c = ch & 31;
      int sc = (c ^ (row & 7)) << 4;
      ulonglong2 v = {0ull, 0ull};
      if (row < n) v = *(const ulonglong2*)(sb + (size_t)(r0 + row) * HH + c * 8);
      *(ulonglong2*)((char*)st + row * 512 + sc) = v;
    }
    __syncthreads();
    const int lane = tid & 63, wid = tid >> 6;
    const int l15 = lane & 15, q = lane >> 4;
    const int x7 = l15 & 7;
    const char* stc = (const char*)st;
    f32x4 acc0 = {0.f, 0.f, 0.f, 0.f};
    f32x4 acc1 = acc0, acc2 = acc0, acc3 = acc0;
    const int arow = wid * 16 + l15;
#pragma unroll
    for (int kk = 0; kk < 8; kk++) {
      int kc = ((kk * 4 + q) ^ x7) << 4;
      bf16x8 a  = *(const bf16x8*)(stc + arow * 512 + kc);
      bf16x8 b0 = *(const bf16x8*)(stc + l15 * 512 + kc);
      bf16x8 b1 = *(const bf16x8*)(stc + (16 + l15) * 512 + kc);
      bf16x8 b2 = *(const bf16x8*)(stc + (32 + l15) * 512 + kc);
      bf16x8 b3 = *(const bf16x8*)(stc + (48 + l15) * 512 + kc);
      acc0 = __builtin_amdgcn_mfma_f32_16x16x32_bf16(a, b0, acc0, 0, 0, 0);
      acc1 = __builtin_amdgcn_mfma_f32_16x16x32_bf16(a, b1, acc1, 0, 0, 0);
      acc2 = __builtin_amdgcn_mfma_f32_16x16x32_bf16(a, b2, acc2, 0, 0, 0);
      acc3 = __builtin_amdgcn_mfma_f32_16x16x32_bf16(a, b3, acc3, 0, 0, 0);
    }
    // masked softmax, fully in registers. D row = wid*16 + q*4 + i, col = t*16 + l15.
    float mi[4], e0[4], e1[4], e2[4], e3[4], inv[4];
#pragma unroll
    for (int i = 0; i < 4; i++) {
      float mm = (l15 < n) ? acc0[i] : -1e30f;
      if (16 + l15 < n) mm = fmaxf(mm, acc1[i]);
      if (32 + l15 < n) mm = fmaxf(mm, acc2[i]);
      if (48 + l15 < n) mm = fmaxf(mm, acc3[i]);
      mi[i] = mm;
    }
#pragma unroll
    for (int off = 1; off < 16; off <<= 1)
#pragma unroll
      for (int i = 0; i < 4; i++) mi[i] = fmaxf(mi[i], __shfl_xor(mi[i], off));
#pragma unroll
    for (int i = 0; i < 4; i++) {
      e0[i] = (l15 < n)      ? __expf(acc0[i] - mi[i]) : 0.f;
      e1[i] = (16 + l15 < n) ? __expf(acc1[i] - mi[i]) : 0.f;
      e2[i] = (32 + l15 < n) ? __expf(acc2[i] - mi[i]) : 0.f;
      e3[i] = (48 + l15 < n) ? __expf(acc3[i] - mi[i]) : 0.f;
      inv[i] = e0[i] + e1[i] + e2[i] + e3[i];
    }
#pragma unroll
    for (int off = 1; off < 16; off <<= 1)
#pragma unroll
      for (int i = 0; i < 4; i++) inv[i] += __shfl_xor(inv[i], off);
#pragma unroll
    for (int i = 0; i < 4; i++) inv[i] = 1.f / inv[i];
    // column partial sums of attn, masked by valid rows
    float cs[4];
#pragma unroll
    for (int t = 0; t < 4; t++) {
      const float* et = t == 0 ? e0 : t == 1 ? e1 : t == 2 ? e2 : e3;
      float c4 = 0.f;
#pragma unroll
      for (int i = 0; i < 4; i++) {
        int row = wid * 16 + q * 4 + i;
        c4 += (row < n) ? et[i] * inv[i] : 0.f;
      }
      cs[t] = c4;
    }
#pragma unroll
    for (int t = 0; t < 4; t++) {
      cs[t] += __shfl_xor(cs[t], 16);
      cs[t] += __shfl_xor(cs[t], 32);
    }
    if (lane < 16) {
#pragma unroll
      for (int t = 0; t < 4; t++) atomicAdd(&colw[t * 16 + l15], cs[t]);
    }
    __syncthreads();
  } else {
    // fallback scalar path (n>64): correct, slow, not expected to be taken
    int nn = n > 256 ? 256 : n;
    __syncthreads();
    int wid = tid >> 6, lane = tid & 63;
    for (int i = wid; i < nn; i += 4) {
      const ushort* si = sb + (size_t)(r0 + i) * HH;
      float d[4];
      int j[4];
#pragma unroll
      for (int u = 0; u < 4; u++) {
        j[u] = lane + u * 64;
        d[u] = (j[u] < nn) ? dotbf(si, sb + (size_t)(r0 + j[u]) * HH) : -1e30f;
      }
      float m = fmaxf(fmaxf(d[0], d[1]), fmaxf(d[2], d[3]));
#pragma unroll
      for (int off = 32; off; off >>= 1) m = fmaxf(m, __shfl_xor(m, off));
      float e[4], ss = 0.f;
#pragma unroll
      for (int u = 0; u < 4; u++) { e[u] = (j[u] < nn) ? __expf(d[u] - m) : 0.f; ss += e[u]; }
#pragma unroll
      for (int off = 32; off; off >>= 1) ss += __shfl_xor(ss, off);
      float iv = 1.f / ss;
#pragma unroll
      for (int u = 0; u < 4; u++)
        if (j[u] < nn) atomicAdd(&colw[j[u]], e[u] * iv);
    }
    __syncthreads();
  }
  // xagg[g][c] = sum_j colw[j] * h[r0+j][c]
  int c = tid;
  int nn = n > 256 ? 256 : n;
  float agg = 0.f;
#pragma unroll 8
  for (int jj = 0; jj < nn; jj++)
    agg = fmaf(colw[jj], bf2f(h[(size_t)(r0 + jj) * HH + c]), agg);
  xagg[(size_t)g * HH + c] = agg;
}

// ---------------- rho: out = relu(relu(xagg@r1w+r1b)@r2w+r2b), [256,256] ----------
__global__ __launch_bounds__(256) void k_rho(const float* __restrict__ xagg,
                                             const float* __restrict__ r1w,
                                             const float* __restrict__ r1b,
                                             const float* __restrict__ r2w,
                                             const float* __restrict__ r2b,
                                             float* __restrict__ out) {
  int g = blockIdx.x;
  int t = threadIdx.x;
  __shared__ float xa[256], t1[256];
  xa[t] = xagg[(size_t)g * HH + t];
  __syncthreads();
  float acc = r1b[t];
#pragma unroll 8
  for (int k = 0; k < HH; k++) acc = fmaf(xa[k], r1w[k * HH + t], acc);
  t1[t] = fmaxf(acc, 0.f);
  __syncthreads();
  acc = r2b[t];
#pragma unroll 8
  for (int k = 0; k < HH; k++) acc = fmaf(t1[k], r2w[k * HH + t], acc);
  out[(size_t)g * HH + t] = fmaxf(acc, 0.f);
}

// ---------------- launcher ----------------
extern "C" void kernel_launch(void* const* d_in, const int* in_sizes, int n_in,
                              void* d_out, int out_size, void* d_ws, size_t ws_size,
                              hipStream_t stream) {
  const float* x   = (const float*)d_in[0];
  const int* batch = (const int*)d_in[1];
  const float* aw  = (const float*)d_in[3];
  const float* ab  = (const float*)d_in[4];
  const float* p1w = (const float*)d_in[5];
  const float* p1b = (const float*)d_in[6];
  const float* p2w = (const float*)d_in[7];
  const float* p2b = (const float*)d_in[8];
  const float* r1w = (const float*)d_in[9];
  const float* r1b = (const float*)d_in[10];
  const float* r2w = (const float*)d_in[11];
  const float* r2b = (const float*)d_in[12];
  float* out = (float*)d_out;

  char* ws = (char*)d_ws;
  ushort* xb   = (ushort*)(ws);                                   // 4 MB
  ushort* h1b  = (ushort*)(ws + (size_t)4 * 1024 * 1024);         // 4 MB
  ushort* hb   = (ushort*)(ws + (size_t)8 * 1024 * 1024);         // 4 MB
  ushort* sb16 = (ushort*)(ws + (size_t)12 * 1024 * 1024);        // 4 MB
  ushort* wT1  = (ushort*)(ws + (size_t)16 * 1024 * 1024);        // 128 KB
  ushort* wT2  = wT1 + 65536;                                     // 128 KB
  ushort* wTa  = wT2 + 65536;                                     // 128 KB
  float*  xagg = (float*)(ws + (size_t)16 * 1024 * 1024 + 512 * 1024);  // 256 KB
  int*    rsb  = (int*)(ws + (size_t)16 * 1024 * 1024 + 512 * 1024 + 256 * 1024);

  k_prep<<<dim3(2817), dim3(256), 0, stream>>>(x, xb, p1w, p2w, aw, wT1, wT2, wTa, batch, rsb);
  k_gemm<<<dim3(128, 4), dim3(256), 0, stream>>>(xb, wT1, p1b, h1b, 1);
  k_gemm<<<dim3(128, 4), dim3(256), 0, stream>>>(h1b, wT2, p2b, hb, 1);
  k_gemm<<<dim3(128, 4), dim3(256), 0, stream>>>(hb, wTa, ab, sb16, 0);
  k_attn<<<dim3(256), dim3(256), 0, stream>>>(sb16, hb, rsb, xagg);
  k_rho<<<dim3(256), dim3(256), 0, stream>>>(xagg, r1w, r1b, r2w, r2b, out);
}

// Round 3
// 42.301 us; speedup vs baseline: 3.9766x; 1.8199x over previous
//
#include <hip/hip_runtime.h>
#include <hip/hip_bf16.h>
#include <stdint.h>

#define NN 8192
#define HH 256
#define GG 256
#define PR 32   // rows per k_phi block

typedef __bf16 bf16x8 __attribute__((ext_vector_type(8)));
typedef float f32x4 __attribute__((ext_vector_type(4)));
typedef unsigned short u16v8 __attribute__((ext_vector_type(8)));

__device__ __forceinline__ ushort f2bf(float f) {
  union { float f; uint32_t u; } v; v.f = f;
  uint32_t u = v.u;
  u += 0x7fffu + ((u >> 16) & 1u);   // RNE
  return (ushort)(u >> 16);
}
__device__ __forceinline__ float bf2f(ushort h) {
  union { uint32_t u; float f; } v; v.u = ((uint32_t)h) << 16;
  return v.f;
}

// ---------------- prep: transpose+convert weights, rowstarts ----------------
__global__ __launch_bounds__(256) void k_prep(const float* __restrict__ w0,
                                              const float* __restrict__ w1,
                                              const float* __restrict__ w2,
                                              ushort* __restrict__ o0,
                                              ushort* __restrict__ o1,
                                              ushort* __restrict__ o2,
                                              const int* __restrict__ batch,
                                              int* __restrict__ rs) {
  int b = blockIdx.x, t = threadIdx.x;
  if (b < 768) {
    int mat = b >> 8, nrow = b & 255;
    const float* w = mat == 0 ? w0 : mat == 1 ? w1 : w2;
    ushort* o = mat == 0 ? o0 : mat == 1 ? o1 : o2;
    o[nrow * HH + t] = f2bf(w[t * HH + nrow]);
  } else {
    for (int g = t; g <= GG; g += 256) {
      if (g == GG) { rs[GG] = NN; continue; }
      int lo = 0, hi = NN;
      while (lo < hi) { int mid = (lo + hi) >> 1; if (batch[mid] < g) lo = mid + 1; else hi = mid; }
      rs[g] = lo;
    }
  }
}

// ---------------- fused phi: 3 x (GEMM 256x256 + bias [+relu]) --------------
// Weight LDS layout: linear 16B chunks, chunk index within row XOR-swizzled at
// the GLOBAL SOURCE (rule: gload_lds writes linearly; swizzle source + read).
__device__ __forceinline__ void load_w_lds(const ushort* __restrict__ wt,
                                           ushort* wl, int tid) {
#pragma unroll
  for (int it = 0; it < 16; ++it) {
    int chunk = it * 512 + tid;
    int row = chunk >> 5, c = chunk & 31;
    int src = (chunk & ~31) | (c ^ (row & 7));
    __builtin_amdgcn_global_load_lds(
        (const __attribute__((address_space(1))) uint32_t*)(wt + src * 8),
        (__attribute__((address_space(3))) uint32_t*)(wl + chunk * 8),
        16, 0, 0);
  }
}

__global__ __launch_bounds__(512, 1) void k_phi(const float* __restrict__ x,
    const ushort* __restrict__ wt1, const float* __restrict__ b1,
    const ushort* __restrict__ wt2, const float* __restrict__ b2,
    const ushort* __restrict__ wta, const float* __restrict__ ba,
    ushort* __restrict__ hb, ushort* __restrict__ sb) {
  __shared__ ushort wl[HH * HH];    // 128 KB
  __shared__ ushort act[PR * HH];   // 16 KB, chunk c ^= (row&7)
  const int tid = threadIdx.x;
  const int rowbase = blockIdx.x * PR;

  load_w_lds(wt1, wl, tid);   // async w1 -> LDS

  // stage x rows (f32 -> bf16, swizzled)
#pragma unroll
  for (int it = 0; it < 2; ++it) {
    int chunk = it * 512 + tid;
    int row = chunk >> 5, c = chunk & 31;
    const float* xp = x + (size_t)(rowbase + row) * HH + c * 8;
    float4 v0 = *(const float4*)xp;
    float4 v1 = *(const float4*)(xp + 4);
    u16v8 o;
    o[0] = f2bf(v0.x); o[1] = f2bf(v0.y); o[2] = f2bf(v0.z); o[3] = f2bf(v0.w);
    o[4] = f2bf(v1.x); o[5] = f2bf(v1.y); o[6] = f2bf(v1.z); o[7] = f2bf(v1.w);
    int dst = (chunk & ~31) | (c ^ (row & 7));
    *(u16v8*)(act + dst * 8) = o;
  }
  __syncthreads();

  const int lane = tid & 63, wid = tid >> 6;
  const int l15 = lane & 15, q = lane >> 4, x7 = l15 & 7;
  const int wr = (wid & 1) * 16;    // row offset within block tile
  const int wc = (wid >> 1) * 64;   // col offset
  const int ro = wr + q * 4;        // C-frag base row

#define PHI_MFMA(ACC)                                                          \
  {                                                                            \
    _Pragma("unroll")                                                          \
    for (int kk = 0; kk < 8; ++kk) {                                           \
      int kc = (kk * 4 + q) ^ x7;                                              \
      bf16x8 a = *(const bf16x8*)(act + ((wr + l15) * 32 + kc) * 8);           \
      _Pragma("unroll")                                                        \
      for (int nt = 0; nt < 4; ++nt) {                                         \
        bf16x8 b = *(const bf16x8*)(wl + ((wc + nt * 16 + l15) * 32 + kc) * 8);\
        ACC[nt] = __builtin_amdgcn_mfma_f32_16x16x32_bf16(a, b, ACC[nt], 0, 0, 0); \
      }                                                                        \
    }                                                                          \
  }

  // ---- layer 1 ----
  f32x4 acc[4] = {{0.f,0.f,0.f,0.f},{0.f,0.f,0.f,0.f},{0.f,0.f,0.f,0.f},{0.f,0.f,0.f,0.f}};
  PHI_MFMA(acc);
  __syncthreads();                    // everyone done reading act+wl
  load_w_lds(wt2, wl, tid);           // prefetch w2
#pragma unroll
  for (int nt = 0; nt < 4; ++nt) {
    int col = wc + nt * 16 + l15;
    float bv = b1[col];
#pragma unroll
    for (int i = 0; i < 4; ++i) {
      float v = fmaxf(acc[nt][i] + bv, 0.f);
      int r = ro + i;
      int cc = (col >> 3) ^ (r & 7);
      act[(r * 32 + cc) * 8 + (col & 7)] = f2bf(v);
    }
  }
  __syncthreads();

  // ---- layer 2 ----
  f32x4 acc2[4] = {{0.f,0.f,0.f,0.f},{0.f,0.f,0.f,0.f},{0.f,0.f,0.f,0.f},{0.f,0.f,0.f,0.f}};
  PHI_MFMA(acc2);
  __syncthreads();
  load_w_lds(wta, wl, tid);           // prefetch wa
#pragma unroll
  for (int nt = 0; nt < 4; ++nt) {
    int col = wc + nt * 16 + l15;
    float bv = b2[col];
#pragma unroll
    for (int i = 0; i < 4; ++i) {
      float v = fmaxf(acc2[nt][i] + bv, 0.f);
      int r = ro + i;
      int cc = (col >> 3) ^ (r & 7);
      act[(r * 32 + cc) * 8 + (col & 7)] = f2bf(v);
    }
  }
  __syncthreads();

  // ---- layer 3: s = h @ aw + ab (no relu) ----
  f32x4 acc3[4] = {{0.f,0.f,0.f,0.f},{0.f,0.f,0.f,0.f},{0.f,0.f,0.f,0.f},{0.f,0.f,0.f,0.f}};
  PHI_MFMA(acc3);
#pragma unroll
  for (int nt = 0; nt < 4; ++nt) {
    int col = wc + nt * 16 + l15;
    float bv = ba[col];
#pragma unroll
    for (int i = 0; i < 4; ++i)
      sb[(size_t)(rowbase + ro + i) * HH + col] = f2bf(acc3[nt][i] + bv);
  }
  // copy h (current act) to global, unswizzling
#pragma unroll
  for (int it = 0; it < 2; ++it) {
    int chunk = it * 512 + tid;
    int row = chunk >> 5, c = chunk & 31;
    int srcp = (chunk & ~31) | (c ^ (row & 7));
    u16v8 v = *(const u16v8*)(act + srcp * 8);
    *(u16v8*)(hb + (size_t)rowbase * HH + chunk * 8) = v;
  }
#undef PHI_MFMA
}

// ---------------- per-graph attention + aggregation (MFMA, n<=64) -----------
__device__ __forceinline__ float dotbf(const ushort* __restrict__ a,
                                       const ushort* __restrict__ b) {
  float acc = 0.f;
  for (int k = 0; k < HH; k += 2) {
    acc = fmaf(bf2f(a[k]), bf2f(b[k]), acc);
    acc = fmaf(bf2f(a[k + 1]), bf2f(b[k + 1]), acc);
  }
  return acc;
}

__global__ __launch_bounds__(256) void k_attn(const ushort* __restrict__ sb,
                                              const ushort* __restrict__ h,
                                              const int* __restrict__ rs,
                                              float* __restrict__ xagg) {
  int g = blockIdx.x;
  int r0 = rs[g], r1 = rs[g + 1];
  int n = r1 - r0;
  __shared__ ushort st[64 * 256];   // swizzled 16B chunks
  __shared__ float colw[256];
  int tid = threadIdx.x;
  colw[tid] = 0.f;
  if (n <= 64) {
    for (int ch = tid; ch < 64 * 32; ch += 256) {
      int row = ch >> 5, c = ch & 31;
      int sc = (c ^ (row & 7)) << 4;
      ulonglong2 v = {0ull, 0ull};
      if (row < n) v = *(const ulonglong2*)(sb + (size_t)(r0 + row) * HH + c * 8);
      *(ulonglong2*)((char*)st + row * 512 + sc) = v;
    }
    __syncthreads();
    const int lane = tid & 63, wid = tid >> 6;
    const int l15 = lane & 15, q = lane >> 4;
    const int x7 = l15 & 7;
    const char* stc = (const char*)st;
    f32x4 acc0 = {0.f, 0.f, 0.f, 0.f};
    f32x4 acc1 = acc0, acc2 = acc0, acc3 = acc0;
    const int arow = wid * 16 + l15;
#pragma unroll
    for (int kk = 0; kk < 8; kk++) {
      int kc = ((kk * 4 + q) ^ x7) << 4;
      bf16x8 a  = *(const bf16x8*)(stc + arow * 512 + kc);
      bf16x8 b0 = *(const bf16x8*)(stc + l15 * 512 + kc);
      bf16x8 b1 = *(const bf16x8*)(stc + (16 + l15) * 512 + kc);
      bf16x8 b2 = *(const bf16x8*)(stc + (32 + l15) * 512 + kc);
      bf16x8 b3 = *(const bf16x8*)(stc + (48 + l15) * 512 + kc);
      acc0 = __builtin_amdgcn_mfma_f32_16x16x32_bf16(a, b0, acc0, 0, 0, 0);
      acc1 = __builtin_amdgcn_mfma_f32_16x16x32_bf16(a, b1, acc1, 0, 0, 0);
      acc2 = __builtin_amdgcn_mfma_f32_16x16x32_bf16(a, b2, acc2, 0, 0, 0);
      acc3 = __builtin_amdgcn_mfma_f32_16x16x32_bf16(a, b3, acc3, 0, 0, 0);
    }
    float mi[4], e0[4], e1[4], e2[4], e3[4], inv[4];
#pragma unroll
    for (int i = 0; i < 4; i++) {
      float mm = (l15 < n) ? acc0[i] : -1e30f;
      if (16 + l15 < n) mm = fmaxf(mm, acc1[i]);
      if (32 + l15 < n) mm = fmaxf(mm, acc2[i]);
      if (48 + l15 < n) mm = fmaxf(mm, acc3[i]);
      mi[i] = mm;
    }
#pragma unroll
    for (int off = 1; off < 16; off <<= 1)
#pragma unroll
      for (int i = 0; i < 4; i++) mi[i] = fmaxf(mi[i], __shfl_xor(mi[i], off));
#pragma unroll
    for (int i = 0; i < 4; i++) {
      e0[i] = (l15 < n)      ? __expf(acc0[i] - mi[i]) : 0.f;
      e1[i] = (16 + l15 < n) ? __expf(acc1[i] - mi[i]) : 0.f;
      e2[i] = (32 + l15 < n) ? __expf(acc2[i] - mi[i]) : 0.f;
      e3[i] = (48 + l15 < n) ? __expf(acc3[i] - mi[i]) : 0.f;
      inv[i] = e0[i] + e1[i] + e2[i] + e3[i];
    }
#pragma unroll
    for (int off = 1; off < 16; off <<= 1)
#pragma unroll
      for (int i = 0; i < 4; i++) inv[i] += __shfl_xor(inv[i], off);
#pragma unroll
    for (int i = 0; i < 4; i++) inv[i] = 1.f / inv[i];
    float cs[4];
#pragma unroll
    for (int t = 0; t < 4; t++) {
      const float* et = t == 0 ? e0 : t == 1 ? e1 : t == 2 ? e2 : e3;
      float c4 = 0.f;
#pragma unroll
      for (int i = 0; i < 4; i++) {
        int row = wid * 16 + q * 4 + i;
        c4 += (row < n) ? et[i] * inv[i] : 0.f;
      }
      cs[t] = c4;
    }
#pragma unroll
    for (int t = 0; t < 4; t++) {
      cs[t] += __shfl_xor(cs[t], 16);
      cs[t] += __shfl_xor(cs[t], 32);
    }
    if (lane < 16) {
#pragma unroll
      for (int t = 0; t < 4; t++) atomicAdd(&colw[t * 16 + l15], cs[t]);
    }
    __syncthreads();
  } else {
    int nn = n > 256 ? 256 : n;
    __syncthreads();
    int wid = tid >> 6, lane = tid & 63;
    for (int i = wid; i < nn; i += 4) {
      const ushort* si = sb + (size_t)(r0 + i) * HH;
      float d[4];
      int j[4];
#pragma unroll
      for (int u = 0; u < 4; u++) {
        j[u] = lane + u * 64;
        d[u] = (j[u] < nn) ? dotbf(si, sb + (size_t)(r0 + j[u]) * HH) : -1e30f;
      }
      float m = fmaxf(fmaxf(d[0], d[1]), fmaxf(d[2], d[3]));
#pragma unroll
      for (int off = 32; off; off >>= 1) m = fmaxf(m, __shfl_xor(m, off));
      float e[4], ss = 0.f;
#pragma unroll
      for (int u = 0; u < 4; u++) { e[u] = (j[u] < nn) ? __expf(d[u] - m) : 0.f; ss += e[u]; }
#pragma unroll
      for (int off = 32; off; off >>= 1) ss += __shfl_xor(ss, off);
      float iv = 1.f / ss;
#pragma unroll
      for (int u = 0; u < 4; u++)
        if (j[u] < nn) atomicAdd(&colw[j[u]], e[u] * iv);
    }
    __syncthreads();
  }
  int c = tid;
  int nn = n > 256 ? 256 : n;
  float agg = 0.f;
#pragma unroll 8
  for (int jj = 0; jj < nn; jj++)
    agg = fmaf(colw[jj], bf2f(h[(size_t)(r0 + jj) * HH + c]), agg);
  xagg[(size_t)g * HH + c] = agg;
}

// ---------------- rho ----------------
__global__ __launch_bounds__(256) void k_rho(const float* __restrict__ xagg,
                                             const float* __restrict__ r1w,
                                             const float* __restrict__ r1b,
                                             const float* __restrict__ r2w,
                                             const float* __restrict__ r2b,
                                             float* __restrict__ out) {
  int g = blockIdx.x;
  int t = threadIdx.x;
  __shared__ float xa[256], t1[256];
  xa[t] = xagg[(size_t)g * HH + t];
  __syncthreads();
  float a0 = 0.f, a1 = 0.f, a2 = 0.f, a3 = 0.f;
#pragma unroll 4
  for (int k = 0; k < HH; k += 4) {
    a0 = fmaf(xa[k],     r1w[(k)     * HH + t], a0);
    a1 = fmaf(xa[k + 1], r1w[(k + 1) * HH + t], a1);
    a2 = fmaf(xa[k + 2], r1w[(k + 2) * HH + t], a2);
    a3 = fmaf(xa[k + 3], r1w[(k + 3) * HH + t], a3);
  }
  t1[t] = fmaxf(r1b[t] + (a0 + a1) + (a2 + a3), 0.f);
  __syncthreads();
  a0 = a1 = a2 = a3 = 0.f;
#pragma unroll 4
  for (int k = 0; k < HH; k += 4) {
    a0 = fmaf(t1[k],     r2w[(k)     * HH + t], a0);
    a1 = fmaf(t1[k + 1], r2w[(k + 1) * HH + t], a1);
    a2 = fmaf(t1[k + 2], r2w[(k + 2) * HH + t], a2);
    a3 = fmaf(t1[k + 3], r2w[(k + 3) * HH + t], a3);
  }
  out[(size_t)g * HH + t] = fmaxf(r2b[t] + (a0 + a1) + (a2 + a3), 0.f);
}

// ---------------- launcher ----------------
extern "C" void kernel_launch(void* const* d_in, const int* in_sizes, int n_in,
                              void* d_out, int out_size, void* d_ws, size_t ws_size,
                              hipStream_t stream) {
  const float* x   = (const float*)d_in[0];
  const int* batch = (const int*)d_in[1];
  const float* aw  = (const float*)d_in[3];
  const float* ab  = (const float*)d_in[4];
  const float* p1w = (const float*)d_in[5];
  const float* p1b = (const float*)d_in[6];
  const float* p2w = (const float*)d_in[7];
  const float* p2b = (const float*)d_in[8];
  const float* r1w = (const float*)d_in[9];
  const float* r1b = (const float*)d_in[10];
  const float* r2w = (const float*)d_in[11];
  const float* r2b = (const float*)d_in[12];
  float* out = (float*)d_out;

  char* ws = (char*)d_ws;
  ushort* hb   = (ushort*)(ws);                                   // 4 MB
  ushort* sb16 = (ushort*)(ws + (size_t)4 * 1024 * 1024);         // 4 MB
  ushort* wT1  = (ushort*)(ws + (size_t)8 * 1024 * 1024);         // 128 KB
  ushort* wT2  = wT1 + 65536;                                     // 128 KB
  ushort* wTa  = wT2 + 65536;                                     // 128 KB
  float*  xagg = (float*)(ws + (size_t)8 * 1024 * 1024 + 512 * 1024);   // 256 KB
  int*    rsb  = (int*)(ws + (size_t)8 * 1024 * 1024 + 768 * 1024);

  k_prep<<<dim3(769), dim3(256), 0, stream>>>(p1w, p2w, aw, wT1, wT2, wTa, batch, rsb);
  k_phi<<<dim3(256), dim3(512), 0, stream>>>(x, wT1, p1b, wT2, p2b, wTa, ab, hb, sb16);
  k_attn<<<dim3(256), dim3(256), 0, stream>>>(sb16, hb, rsb, xagg);
  k_rho<<<dim3(256), dim3(256), 0, stream>>>(xagg, r1w, r1b, r2w, r2b, out);
}

// Round 4
// 38.378 us; speedup vs baseline: 4.3831x; 1.1022x over previous
//
#include <hip/hip_runtime.h>
#include <hip/hip_bf16.h>
#include <stdint.h>

#define NN 8192
#define HH 256
#define GG 256
#define PR 32   // rows per k_phi / k_rho2 block

typedef __bf16 bf16x8 __attribute__((ext_vector_type(8)));
typedef float f32x4 __attribute__((ext_vector_type(4)));
typedef unsigned short u16v8 __attribute__((ext_vector_type(8)));

__device__ __forceinline__ ushort f2bf(float f) {
  union { float f; uint32_t u; } v; v.f = f;
  uint32_t u = v.u;
  u += 0x7fffu + ((u >> 16) & 1u);   // RNE
  return (ushort)(u >> 16);
}
__device__ __forceinline__ float bf2f(ushort h) {
  union { uint32_t u; float f; } v; v.u = ((uint32_t)h) << 16;
  return v.f;
}

// ---------------- prep: coalesced tile-transpose 5 weights (f32->bf16 [n][k]),
// rowstarts. Grid: 80 transpose blocks (5 mats x 16 tiles) + 1 rowstart block.
__global__ __launch_bounds__(256) void k_prep(const float* __restrict__ w0,
                                              const float* __restrict__ w1,
                                              const float* __restrict__ w2,
                                              const float* __restrict__ w3,
                                              const float* __restrict__ w4,
                                              ushort* __restrict__ o0,
                                              ushort* __restrict__ o1,
                                              ushort* __restrict__ o2,
                                              ushort* __restrict__ o3,
                                              ushort* __restrict__ o4,
                                              const int* __restrict__ batch,
                                              int* __restrict__ rs) {
  int b = blockIdx.x, t = threadIdx.x;
  if (b < 80) {
    int mat = b >> 4, tile = b & 15;
    int tr = (tile >> 2) * 64, tc = (tile & 3) * 64;
    const float* w = mat == 0 ? w0 : mat == 1 ? w1 : mat == 2 ? w2 : mat == 3 ? w3 : w4;
    ushort* o = mat == 0 ? o0 : mat == 1 ? o1 : mat == 2 ? o2 : mat == 3 ? o3 : o4;
    __shared__ float tileb[64][65];
    int rr = t >> 2, cg = (t & 3) * 16;
    const float* src = w + (size_t)(tr + rr) * HH + tc + cg;
#pragma unroll
    for (int j = 0; j < 4; ++j) {
      float4 v = *(const float4*)(src + j * 4);
      tileb[rr][cg + j * 4 + 0] = v.x;
      tileb[rr][cg + j * 4 + 1] = v.y;
      tileb[rr][cg + j * 4 + 2] = v.z;
      tileb[rr][cg + j * 4 + 3] = v.w;
    }
    __syncthreads();
    // write out[n][k]: n = tc+rn, k = tr+kg+j
    int rn = t >> 2, kg = (t & 3) * 16;
    u16v8 a, c;
#pragma unroll
    for (int j = 0; j < 8; ++j) a[j] = f2bf(tileb[kg + j][rn]);
#pragma unroll
    for (int j = 0; j < 8; ++j) c[j] = f2bf(tileb[kg + 8 + j][rn]);
    ushort* dst = o + (size_t)(tc + rn) * HH + tr + kg;
    *(u16v8*)dst = a;
    *(u16v8*)(dst + 8) = c;
  } else {
    for (int g = t; g <= GG; g += 256) {
      if (g == GG) { rs[GG] = NN; continue; }
      int lo = 0, hi = NN;
      while (lo < hi) { int mid = (lo + hi) >> 1; if (batch[mid] < g) lo = mid + 1; else hi = mid; }
      rs[g] = lo;
    }
  }
}

// Weight LDS load: linear dest, source chunk-swizzled (gload_lds writes linearly).
__device__ __forceinline__ void load_w_lds(const ushort* __restrict__ wt,
                                           ushort* wl, int tid) {
#pragma unroll
  for (int it = 0; it < 16; ++it) {
    int chunk = it * 512 + tid;
    int row = chunk >> 5, c = chunk & 31;
    int src = (chunk & ~31) | (c ^ (row & 7));
    __builtin_amdgcn_global_load_lds(
        (const __attribute__((address_space(1))) uint32_t*)(wt + src * 8),
        (__attribute__((address_space(3))) uint32_t*)(wl + chunk * 8),
        16, 0, 0);
  }
}

#define PHI_MFMA(ACC)                                                          \
  {                                                                            \
    _Pragma("unroll")                                                          \
    for (int kk = 0; kk < 8; ++kk) {                                           \
      int kc = (kk * 4 + q) ^ x7;                                              \
      bf16x8 a = *(const bf16x8*)(act + ((wr + l15) * 32 + kc) * 8);           \
      _Pragma("unroll")                                                        \
      for (int nt = 0; nt < 4; ++nt) {                                         \
        bf16x8 b = *(const bf16x8*)(wl + ((wc + nt * 16 + l15) * 32 + kc) * 8);\
        ACC[nt] = __builtin_amdgcn_mfma_f32_16x16x32_bf16(a, b, ACC[nt], 0, 0, 0); \
      }                                                                        \
    }                                                                          \
  }

// ---------------- fused phi: 3 x (GEMM 256x256 + bias [+relu]) --------------
__global__ __launch_bounds__(512, 1) void k_phi(const float* __restrict__ x,
    const ushort* __restrict__ wt1, const float* __restrict__ b1,
    const ushort* __restrict__ wt2, const float* __restrict__ b2,
    const ushort* __restrict__ wta, const float* __restrict__ ba,
    ushort* __restrict__ hb, ushort* __restrict__ sb) {
  __shared__ ushort wl[HH * HH];    // 128 KB
  __shared__ ushort act[PR * HH];   // 16 KB, chunk c ^= (row&7)
  const int tid = threadIdx.x;
  const int rowbase = blockIdx.x * PR;

  load_w_lds(wt1, wl, tid);   // async w1 -> LDS

#pragma unroll
  for (int it = 0; it < 2; ++it) {
    int chunk = it * 512 + tid;
    int row = chunk >> 5, c = chunk & 31;
    const float* xp = x + (size_t)(rowbase + row) * HH + c * 8;
    float4 v0 = *(const float4*)xp;
    float4 v1 = *(const float4*)(xp + 4);
    u16v8 o;
    o[0] = f2bf(v0.x); o[1] = f2bf(v0.y); o[2] = f2bf(v0.z); o[3] = f2bf(v0.w);
    o[4] = f2bf(v1.x); o[5] = f2bf(v1.y); o[6] = f2bf(v1.z); o[7] = f2bf(v1.w);
    int dst = (chunk & ~31) | (c ^ (row & 7));
    *(u16v8*)(act + dst * 8) = o;
  }
  __syncthreads();

  const int lane = tid & 63, wid = tid >> 6;
  const int l15 = lane & 15, q = lane >> 4, x7 = l15 & 7;
  const int wr = (wid & 1) * 16;
  const int wc = (wid >> 1) * 64;
  const int ro = wr + q * 4;

  // ---- layer 1 ----
  f32x4 acc[4] = {{0.f,0.f,0.f,0.f},{0.f,0.f,0.f,0.f},{0.f,0.f,0.f,0.f},{0.f,0.f,0.f,0.f}};
  PHI_MFMA(acc);
  __syncthreads();
  load_w_lds(wt2, wl, tid);
#pragma unroll
  for (int nt = 0; nt < 4; ++nt) {
    int col = wc + nt * 16 + l15;
    float bv = b1[col];
#pragma unroll
    for (int i = 0; i < 4; ++i) {
      float v = fmaxf(acc[nt][i] + bv, 0.f);
      int r = ro + i;
      int cc = (col >> 3) ^ (r & 7);
      act[(r * 32 + cc) * 8 + (col & 7)] = f2bf(v);
    }
  }
  __syncthreads();

  // ---- layer 2 ----
  f32x4 acc2[4] = {{0.f,0.f,0.f,0.f},{0.f,0.f,0.f,0.f},{0.f,0.f,0.f,0.f},{0.f,0.f,0.f,0.f}};
  PHI_MFMA(acc2);
  __syncthreads();
  load_w_lds(wta, wl, tid);
#pragma unroll
  for (int nt = 0; nt < 4; ++nt) {
    int col = wc + nt * 16 + l15;
    float bv = b2[col];
#pragma unroll
    for (int i = 0; i < 4; ++i) {
      float v = fmaxf(acc2[nt][i] + bv, 0.f);
      int r = ro + i;
      int cc = (col >> 3) ^ (r & 7);
      act[(r * 32 + cc) * 8 + (col & 7)] = f2bf(v);
    }
  }
  __syncthreads();

  // ---- layer 3: s = h @ aw + ab ----
  f32x4 acc3[4] = {{0.f,0.f,0.f,0.f},{0.f,0.f,0.f,0.f},{0.f,0.f,0.f,0.f},{0.f,0.f,0.f,0.f}};
  PHI_MFMA(acc3);
#pragma unroll
  for (int nt = 0; nt < 4; ++nt) {
    int col = wc + nt * 16 + l15;
    float bv = ba[col];
#pragma unroll
    for (int i = 0; i < 4; ++i)
      sb[(size_t)(rowbase + ro + i) * HH + col] = f2bf(acc3[nt][i] + bv);
  }
  // copy h (act) to global, unswizzling
#pragma unroll
  for (int it = 0; it < 2; ++it) {
    int chunk = it * 512 + tid;
    int row = chunk >> 5, c = chunk & 31;
    int srcp = (chunk & ~31) | (c ^ (row & 7));
    u16v8 v = *(const u16v8*)(act + srcp * 8);
    *(u16v8*)(hb + (size_t)rowbase * HH + chunk * 8) = v;
  }
}

// ---------------- per-graph attention + aggregation (MFMA, n<=64) -----------
__device__ __forceinline__ float dotbf(const ushort* __restrict__ a,
                                       const ushort* __restrict__ b) {
  float acc = 0.f;
  for (int k = 0; k < HH; k += 2) {
    acc = fmaf(bf2f(a[k]), bf2f(b[k]), acc);
    acc = fmaf(bf2f(a[k + 1]), bf2f(b[k + 1]), acc);
  }
  return acc;
}

__global__ __launch_bounds__(256) void k_attn(const ushort* __restrict__ sb,
                                              const ushort* __restrict__ h,
                                              const int* __restrict__ rs,
                                              float* __restrict__ xagg) {
  int g = blockIdx.x;
  int r0 = rs[g], r1 = rs[g + 1];
  int n = r1 - r0;
  __shared__ ushort st[64 * 256];   // swizzled 16B chunks
  __shared__ float colw[256];
  int tid = threadIdx.x;
  colw[tid] = 0.f;
  if (n <= 64) {
    // stage only live rows (garbage elsewhere is fully masked downstream)
    for (int ch = tid; ch < n * 32; ch += 256) {
      int row = ch >> 5, c = ch & 31;
      int sc = (c ^ (row & 7)) << 4;
      ulonglong2 v = *(const ulonglong2*)(sb + (size_t)(r0 + row) * HH + c * 8);
      *(ulonglong2*)((char*)st + row * 512 + sc) = v;
    }
    __syncthreads();
    const int lane = tid & 63, wid = tid >> 6;
    const int l15 = lane & 15, q = lane >> 4;
    const int x7 = l15 & 7;
    const char* stc = (const char*)st;
    if (wid * 16 < n) {   // wave has live query rows
      f32x4 acc0 = {0.f, 0.f, 0.f, 0.f};
      f32x4 acc1 = acc0, acc2 = acc0, acc3 = acc0;
      const int arow = wid * 16 + l15;
#pragma unroll
      for (int kk = 0; kk < 8; kk++) {
        int kc = ((kk * 4 + q) ^ x7) << 4;
        bf16x8 a  = *(const bf16x8*)(stc + arow * 512 + kc);
        bf16x8 b0 = *(const bf16x8*)(stc + l15 * 512 + kc);
        acc0 = __builtin_amdgcn_mfma_f32_16x16x32_bf16(a, b0, acc0, 0, 0, 0);
        if (n > 16) {
          bf16x8 b1 = *(const bf16x8*)(stc + (16 + l15) * 512 + kc);
          acc1 = __builtin_amdgcn_mfma_f32_16x16x32_bf16(a, b1, acc1, 0, 0, 0);
        }
        if (n > 32) {
          bf16x8 b2 = *(const bf16x8*)(stc + (32 + l15) * 512 + kc);
          acc2 = __builtin_amdgcn_mfma_f32_16x16x32_bf16(a, b2, acc2, 0, 0, 0);
        }
        if (n > 48) {
          bf16x8 b3 = *(const bf16x8*)(stc + (48 + l15) * 512 + kc);
          acc3 = __builtin_amdgcn_mfma_f32_16x16x32_bf16(a, b3, acc3, 0, 0, 0);
        }
      }
      float mi[4], e0[4], e1[4], e2[4], e3[4], inv[4];
#pragma unroll
      for (int i = 0; i < 4; i++) {
        float mm = (l15 < n) ? acc0[i] : -1e30f;
        if (16 + l15 < n) mm = fmaxf(mm, acc1[i]);
        if (32 + l15 < n) mm = fmaxf(mm, acc2[i]);
        if (48 + l15 < n) mm = fmaxf(mm, acc3[i]);
        mi[i] = mm;
      }
#pragma unroll
      for (int off = 1; off < 16; off <<= 1)
#pragma unroll
        for (int i = 0; i < 4; i++) mi[i] = fmaxf(mi[i], __shfl_xor(mi[i], off));
#pragma unroll
      for (int i = 0; i < 4; i++) {
        e0[i] = (l15 < n)      ? __expf(acc0[i] - mi[i]) : 0.f;
        e1[i] = (16 + l15 < n) ? __expf(acc1[i] - mi[i]) : 0.f;
        e2[i] = (32 + l15 < n) ? __expf(acc2[i] - mi[i]) : 0.f;
        e3[i] = (48 + l15 < n) ? __expf(acc3[i] - mi[i]) : 0.f;
        inv[i] = e0[i] + e1[i] + e2[i] + e3[i];
      }
#pragma unroll
      for (int off = 1; off < 16; off <<= 1)
#pragma unroll
        for (int i = 0; i < 4; i++) inv[i] += __shfl_xor(inv[i], off);
#pragma unroll
      for (int i = 0; i < 4; i++) inv[i] = 1.f / inv[i];
      float cs[4];
#pragma unroll
      for (int t = 0; t < 4; t++) {
        const float* et = t == 0 ? e0 : t == 1 ? e1 : t == 2 ? e2 : e3;
        float c4 = 0.f;
#pragma unroll
        for (int i = 0; i < 4; i++) {
          int row = wid * 16 + q * 4 + i;
          c4 += (row < n) ? et[i] * inv[i] : 0.f;
        }
        cs[t] = c4;
      }
#pragma unroll
      for (int t = 0; t < 4; t++) {
        cs[t] += __shfl_xor(cs[t], 16);
        cs[t] += __shfl_xor(cs[t], 32);
      }
      if (lane < 16) {
#pragma unroll
        for (int t = 0; t < 4; t++)
          if (t * 16 < n) atomicAdd(&colw[t * 16 + l15], cs[t]);
      }
    }
    __syncthreads();
  } else {
    int nn = n > 256 ? 256 : n;
    __syncthreads();
    int wid = tid >> 6, lane = tid & 63;
    for (int i = wid; i < nn; i += 4) {
      const ushort* si = sb + (size_t)(r0 + i) * HH;
      float d[4];
      int j[4];
#pragma unroll
      for (int u = 0; u < 4; u++) {
        j[u] = lane + u * 64;
        d[u] = (j[u] < nn) ? dotbf(si, sb + (size_t)(r0 + j[u]) * HH) : -1e30f;
      }
      float m = fmaxf(fmaxf(d[0], d[1]), fmaxf(d[2], d[3]));
#pragma unroll
      for (int off = 32; off; off >>= 1) m = fmaxf(m, __shfl_xor(m, off));
      float e[4], ss = 0.f;
#pragma unroll
      for (int u = 0; u < 4; u++) { e[u] = (j[u] < nn) ? __expf(d[u] - m) : 0.f; ss += e[u]; }
#pragma unroll
      for (int off = 32; off; off >>= 1) ss += __shfl_xor(ss, off);
      float iv = 1.f / ss;
#pragma unroll
      for (int u = 0; u < 4; u++)
        if (j[u] < nn) atomicAdd(&colw[j[u]], e[u] * iv);
    }
    __syncthreads();
  }
  int c = tid;
  int nn = n > 256 ? 256 : n;
  float agg = 0.f;
#pragma unroll 8
  for (int jj = 0; jj < nn; jj++)
    agg = fmaf(colw[jj], bf2f(h[(size_t)(r0 + jj) * HH + c]), agg);
  xagg[(size_t)g * HH + c] = agg;
}

// ---------------- rho via MFMA: out = relu(relu(xagg@r1w+b1)@r2w+b2) --------
// 8 blocks x 32 rows, same structure as k_phi, 2 layers, f32 output.
__global__ __launch_bounds__(512, 1) void k_rho2(const float* __restrict__ xagg,
    const ushort* __restrict__ rt1, const float* __restrict__ b1,
    const ushort* __restrict__ rt2, const float* __restrict__ b2,
    float* __restrict__ out) {
  __shared__ ushort wl[HH * HH];
  __shared__ ushort act[PR * HH];
  const int tid = threadIdx.x;
  const int rowbase = blockIdx.x * PR;

  load_w_lds(rt1, wl, tid);

#pragma unroll
  for (int it = 0; it < 2; ++it) {
    int chunk = it * 512 + tid;
    int row = chunk >> 5, c = chunk & 31;
    const float* xp = xagg + (size_t)(rowbase + row) * HH + c * 8;
    float4 v0 = *(const float4*)xp;
    float4 v1 = *(const float4*)(xp + 4);
    u16v8 o;
    o[0] = f2bf(v0.x); o[1] = f2bf(v0.y); o[2] = f2bf(v0.z); o[3] = f2bf(v0.w);
    o[4] = f2bf(v1.x); o[5] = f2bf(v1.y); o[6] = f2bf(v1.z); o[7] = f2bf(v1.w);
    int dst = (chunk & ~31) | (c ^ (row & 7));
    *(u16v8*)(act + dst * 8) = o;
  }
  __syncthreads();

  const int lane = tid & 63, wid = tid >> 6;
  const int l15 = lane & 15, q = lane >> 4, x7 = l15 & 7;
  const int wr = (wid & 1) * 16;
  const int wc = (wid >> 1) * 64;
  const int ro = wr + q * 4;

  f32x4 acc[4] = {{0.f,0.f,0.f,0.f},{0.f,0.f,0.f,0.f},{0.f,0.f,0.f,0.f},{0.f,0.f,0.f,0.f}};
  PHI_MFMA(acc);
  __syncthreads();
  load_w_lds(rt2, wl, tid);
#pragma unroll
  for (int nt = 0; nt < 4; ++nt) {
    int col = wc + nt * 16 + l15;
    float bv = b1[col];
#pragma unroll
    for (int i = 0; i < 4; ++i) {
      float v = fmaxf(acc[nt][i] + bv, 0.f);
      int r = ro + i;
      int cc = (col >> 3) ^ (r & 7);
      act[(r * 32 + cc) * 8 + (col & 7)] = f2bf(v);
    }
  }
  __syncthreads();

  f32x4 acc2[4] = {{0.f,0.f,0.f,0.f},{0.f,0.f,0.f,0.f},{0.f,0.f,0.f,0.f},{0.f,0.f,0.f,0.f}};
  PHI_MFMA(acc2);
#pragma unroll
  for (int nt = 0; nt < 4; ++nt) {
    int col = wc + nt * 16 + l15;
    float bv = b2[col];
#pragma unroll
    for (int i = 0; i < 4; ++i)
      out[(size_t)(rowbase + ro + i) * HH + col] = fmaxf(acc2[nt][i] + bv, 0.f);
  }
}

// ---------------- launcher ----------------
extern "C" void kernel_launch(void* const* d_in, const int* in_sizes, int n_in,
                              void* d_out, int out_size, void* d_ws, size_t ws_size,
                              hipStream_t stream) {
  const float* x   = (const float*)d_in[0];
  const int* batch = (const int*)d_in[1];
  const float* aw  = (const float*)d_in[3];
  const float* ab  = (const float*)d_in[4];
  const float* p1w = (const float*)d_in[5];
  const float* p1b = (const float*)d_in[6];
  const float* p2w = (const float*)d_in[7];
  const float* p2b = (const float*)d_in[8];
  const float* r1w = (const float*)d_in[9];
  const float* r1b = (const float*)d_in[10];
  const float* r2w = (const float*)d_in[11];
  const float* r2b = (const float*)d_in[12];
  float* out = (float*)d_out;

  char* ws = (char*)d_ws;
  ushort* hb   = (ushort*)(ws);                                   // 4 MB
  ushort* sb16 = (ushort*)(ws + (size_t)4 * 1024 * 1024);         // 4 MB
  ushort* wT1  = (ushort*)(ws + (size_t)8 * 1024 * 1024);         // 128 KB each
  ushort* wT2  = wT1 + 65536;
  ushort* wTa  = wT2 + 65536;
  ushort* rT1  = wTa + 65536;
  ushort* rT2  = rT1 + 65536;
  float*  xagg = (float*)(ws + (size_t)8 * 1024 * 1024 + 640 * 1024);   // 256 KB
  int*    rsb  = (int*)(ws + (size_t)8 * 1024 * 1024 + 896 * 1024);

  k_prep<<<dim3(81), dim3(256), 0, stream>>>(p1w, p2w, aw, r1w, r2w,
                                             wT1, wT2, wTa, rT1, rT2, batch, rsb);
  k_phi<<<dim3(256), dim3(512), 0, stream>>>(x, wT1, p1b, wT2, p2b, wTa, ab, hb, sb16);
  k_attn<<<dim3(256), dim3(256), 0, stream>>>(sb16, hb, rsb, xagg);
  k_rho2<<<dim3(8), dim3(512), 0, stream>>>(xagg, rT1, r1b, rT2, r2b, out);
}